// Round 8
// baseline (118.420 us; speedup 1.0000x reference)
//
#include <hip/hip_runtime.h>
#include <math.h>

#define BB 16
#define SS 8192
#define HH 256
#define MM 16
#define DNC 32           // k_dft chunks: s-split of [0, 4096)
#define DL 128           // s-rows per chunk (4096/DNC)
#define SCH 16           // v per k_synth block
#define SNC 129          // k_synth chunks: 128 full + 1 edge
#define QOFF (BB * MM * 2 * HH)   // 131072: ABp h-half stride

// ws layout (floats): T2 [4096][32] at 0 (131072), ABp [2][BB][MM][2][HH] at
// 131072 (262144 floats).  Total 1.5 MB.
// d_out scratch: Xp [BB][DNC][MM][2][HH] (4.19M floats) at 0, Wt_r at 16M
// floats, Wt_i at 17M floats — all consumed before k_synth overwrites d_out.

// Fused setup: blocks 0..255 build twiddle table T2[s][2k]=cos(2pi k s/SS),
// [2k+1]=sin (s<4096); blocks 256..767 transpose W (Wt[m][h][k']=w[h][k'][m]).
__global__ __launch_bounds__(256) void k_pre(const float* __restrict__ wr,
                                             const float* __restrict__ wi,
                                             float* __restrict__ T2,
                                             float* __restrict__ Wtr,
                                             float* __restrict__ Wti) {
    const int t = threadIdx.x;
    if (blockIdx.x < 256) {
        int idx = blockIdx.x * 256 + t;     // 0 .. 65535
        int s = idx >> 4, k = idx & 15;
        int r = (k * s) & (SS - 1);         // exact angle reduction
        float th = (float)r * (6.28318530717958647692f / (float)SS);
        float sn, cn;
        sincosf(th, &sn, &cn);
        T2[s * 32 + 2 * k]     = cn;
        T2[s * 32 + 2 * k + 1] = sn;
    } else {
        __shared__ float lds[4096 + 256];
        int bid = blockIdx.x - 256;         // 0..511
        int h = bid & 255, y = bid >> 8;
        const float* src = (y == 0 ? wr : wi) + (size_t)h * 4096;
        float* dst = (y == 0 ? Wtr : Wti);
#pragma unroll
        for (int j = 0; j < 16; j++) {
            int i = j * 256 + t;
            lds[i + (i >> 4)] = src[i];
        }
        __syncthreads();
#pragma unroll
        for (int m = 0; m < 16; m++) {
            int i = t * 16 + m;
            dst[(size_t)m * (HH * HH) + (size_t)h * HH + t] = lds[i + (i >> 4)];
        }
    }
}

// Branchless exact-GELU via A&S 7.1.26 erf (|err| ~ 1.5e-7).
__device__ __forceinline__ float fast_gelu(float y) {
    float x  = fabsf(y) * 0.70710678118654752f;
    float t  = __builtin_amdgcn_rcpf(fmaf(0.3275911f, x, 1.0f));
    float e  = __expf(-x * x);
    float p  = fmaf(fmaf(fmaf(fmaf(1.061405429f, t, -1.453152027f), t,
                   1.421413741f), t, -0.284496736f), t, 0.254829592f) * t;
    float erfabs = fmaf(-p, e, 1.0f);
    return fmaf(0.5f * fabsf(y), erfabs, 0.5f * y);
}

// Stage 1: pruned DFT with HALF-fold (rows s and s+4096), forward-streaming.
// X_re[k] = sum_{s<4096} cos(2pi k s/S) * (even k ? u : d),  u=x_s+x_{s+4096},
// X_im analogous with sin; d=x_s-x_{s+4096}.  Two contiguous forward streams,
// no barriers, no LDS, no edge cases.  16 FMA/element.
__global__ __launch_bounds__(256) void k_dft(const float* __restrict__ x,
                                             const float* __restrict__ T2,
                                             float* __restrict__ Xp) {
    const int c = blockIdx.x, b = blockIdx.y, t = threadIdx.x;
    const int s0 = c * DL;
    const float* x0 = x + (size_t)b * SS * HH + (size_t)s0 * HH + t;
    const float* x1 = x0 + (size_t)(SS / 2) * HH;
    const float* tw = T2 + (size_t)s0 * 32;

    float cs[MM], sn[MM];
#pragma unroll
    for (int k = 0; k < MM; k++) { cs[k] = 0.f; sn[k] = 0.f; }

#pragma unroll 4
    for (int i = 0; i < DL; i++) {
        float xa = x0[(size_t)i * HH];
        float xb = x1[(size_t)i * HH];
        float u = xa + xb, d = xa - xb;
        const float4* t4 = (const float4*)(tw + (size_t)i * 32);
#pragma unroll
        for (int j = 0; j < 8; j++) {
            float4 tt = t4[j];                 // uniform address
            cs[2 * j]     = fmaf(tt.x, u, cs[2 * j]);
            sn[2 * j]     = fmaf(tt.y, u, sn[2 * j]);
            cs[2 * j + 1] = fmaf(tt.z, d, cs[2 * j + 1]);
            sn[2 * j + 1] = fmaf(tt.w, d, sn[2 * j + 1]);
        }
    }

    size_t base = ((size_t)(b * DNC + c) * MM) * (2 * HH) + t;
#pragma unroll
    for (int k = 0; k < MM; k++) {
        Xp[base + (size_t)k * (2 * HH)]      = cs[k];
        Xp[base + (size_t)k * (2 * HH) + HH] = sn[k];
    }
}

// Stage 2 (fused reduce+mix, h-split by 2): block (m, b, q) handles h-half
// [q*128, q*128+128).  Phase A: sum Xp over 32 partials (two p-halves across
// thread groups, LDS-combined).  Phase B: partial O[k'] over this h-half:
// X = cs - i*sn;  O[k'] = sum_h X[h]*(wr+i*wi)[h,k',m];
// ABp[q] = scale*Re(O), ABp[q]+HH = -scale*Im(O); k_synth sums the 2 halves.
__global__ __launch_bounds__(256) void k_mix(const float* __restrict__ Xp,
                                             const float* __restrict__ Wtr,
                                             const float* __restrict__ Wti,
                                             float* __restrict__ ABp) {
    const int m = blockIdx.x, b = blockIdx.y, q = blockIdx.z, t = threadIdx.x;
    const int h0 = q * 128;
    __shared__ float tmp[2][2][128];
    __shared__ float xr_s[128], xs_s[128];

    {   // phase A: hh = t&127, p-half = t>>7 (16 p's each)
        int hh = t & 127, ph = t >> 7;
        float s0 = 0.f, s1 = 0.f;
        size_t base = (((size_t)b * DNC + ph * 16) * MM + m) * (2 * HH) + h0 + hh;
        const size_t ps = (size_t)MM * 2 * HH;
#pragma unroll 4
        for (int p = 0; p < 16; p++) {
            s0 += Xp[base + (size_t)p * ps];
            s1 += Xp[base + (size_t)p * ps + HH];
        }
        tmp[ph][0][hh] = s0;
        tmp[ph][1][hh] = s1;
        __syncthreads();
        if (t < 128) {
            xr_s[t] = tmp[0][0][t] + tmp[1][0][t];
            xs_s[t] = tmp[0][1][t] + tmp[1][1][t];
        }
        __syncthreads();
    }

    // phase B: t = k', loop over this h-half
    const float* wr_m = Wtr + (size_t)m * (HH * HH) + (size_t)h0 * HH;
    const float* wi_m = Wti + (size_t)m * (HH * HH) + (size_t)h0 * HH;
    float re = 0.f, im = 0.f;
#pragma unroll 8
    for (int hh = 0; hh < 128; hh++) {
        float a  = wr_m[(size_t)hh * HH + t];   // lane-contiguous, 1KB/wave
        float bw = wi_m[(size_t)hh * HH + t];
        float xr = xr_s[hh];                    // LDS broadcast
        float xs = xs_s[hh];
        re = fmaf(xr, a, re);  re = fmaf(xs, bw, re);
        im = fmaf(xr, bw, im); im = fmaf(-xs, a, im);
    }
    float scale = (m == 0 ? 1.f : 2.f) / (float)SS;
    size_t o = (size_t)q * QOFF + (((size_t)b * MM + m) * 2) * HH + t;
    ABp[o]      = scale * re;
    ABp[o + HH] = -scale * im;
}

// Stage 3: folded synthesis + GELU.  4 outputs per table row:
// y[v]=Pp+Qp, y[4096-v]=Pm-Qm, y[4096+v]=Pm+Qm, y[8192-v]=Pp-Qp
__global__ __launch_bounds__(256) void k_synth(const float* __restrict__ ABp,
                                               const float* __restrict__ T2,
                                               float* __restrict__ out) {
    const int c = blockIdx.x, b = blockIdx.y, h = threadIdx.x;
    float a[MM], bc[MM];
#pragma unroll
    for (int k = 0; k < MM; k++) {
        size_t o = (((size_t)b * MM + k) * 2) * HH + h;
        a[k]  = ABp[o]      + ABp[o + QOFF];
        bc[k] = ABp[o + HH] + ABp[o + HH + QOFF];
    }
    const int nv = (c == SNC - 1) ? 1 : SCH;
    const int v0 = c * SCH;
    float* ob = out + (size_t)b * SS * HH + h;

#pragma unroll 2
    for (int i = 0; i < nv; i++) {
        int v = v0 + i;
        const float4* tw4 = (const float4*)(T2 + (size_t)v * 32);
        float Pe = 0.f, Po = 0.f, Qe = 0.f, Qo = 0.f;
#pragma unroll
        for (int j = 0; j < 8; j++) {
            float4 t = tw4[j];
            Pe = fmaf(a[2 * j],      t.x, Pe);
            Qe = fmaf(bc[2 * j],     t.y, Qe);
            Po = fmaf(a[2 * j + 1],  t.z, Po);
            Qo = fmaf(bc[2 * j + 1], t.w, Qo);
        }
        float Pp = Pe + Po, Pm = Pe - Po, Qp = Qe + Qo, Qm = Qe - Qo;
        ob[(size_t)v * HH]                        = fast_gelu(Pp + Qp);
        ob[(size_t)(SS / 2 - v) * HH]             = fast_gelu(Pm - Qm);
        ob[(size_t)(SS / 2 + v) * HH]             = fast_gelu(Pm + Qm);
        ob[(size_t)((SS - v) & (SS - 1)) * HH]    = fast_gelu(Pp - Qp);
    }
}

extern "C" void kernel_launch(void* const* d_in, const int* in_sizes, int n_in,
                              void* d_out, int out_size, void* d_ws, size_t ws_size,
                              hipStream_t stream) {
    const float* x   = (const float*)d_in[0];
    const float* w_r = (const float*)d_in[1];
    const float* w_i = (const float*)d_in[2];
    float* out = (float*)d_out;
    float* ws  = (float*)d_ws;

    float* T2  = ws;                              // 131072 floats
    float* ABp = ws + 131072;                     // 262144 floats
    float* Xp  = out;                             // 4.19M floats scratch
    float* Wtr = out + (size_t)16 * 1024 * 1024;  // 1M floats scratch
    float* Wti = out + (size_t)17 * 1024 * 1024;  // 1M floats scratch

    hipLaunchKernelGGL(k_pre,   dim3(768), dim3(256), 0, stream, w_r, w_i, T2, Wtr, Wti);
    hipLaunchKernelGGL(k_dft,   dim3(DNC, BB), dim3(256), 0, stream, x, T2, Xp);
    hipLaunchKernelGGL(k_mix,   dim3(MM, BB, 2), dim3(256), 0, stream, Xp, Wtr, Wti, ABp);
    hipLaunchKernelGGL(k_synth, dim3(SNC, BB), dim3(256), 0, stream, ABp, T2, out);
}

// Round 9
// 112.193 us; speedup vs baseline: 1.0555x; 1.0555x over previous
//
#include <hip/hip_runtime.h>
#include <math.h>

#define BB 16
#define SS 8192
#define HH 256
#define MM 16
#define DNC 64           // k_dft chunks: s-split of [0, 4096)
#define DL 64            // s-rows per chunk (4096/DNC)
#define SCH 16           // v per k_synth block
#define SNC 129          // k_synth chunks: 128 full + 1 edge
#define QOFF (BB * MM * 2 * HH)   // 131072: ABp h-half stride

// ws layout (floats): T2 [4096][32] at 0 (131072), ABp [2][BB][MM][2][HH] at
// 131072 (262144 floats).  Total 1.5 MB.
// d_out scratch: Xp [BB][DNC][MM][2][HH] (8.39M floats, 33.5 MB) at 0, Wt_r at
// 16M floats, Wt_i at 17M floats — all consumed before k_synth overwrites.

// Fused setup: blocks 0..255 build twiddle table T2[s][2k]=cos(2pi k s/SS),
// [2k+1]=sin (s<4096); blocks 256..767 transpose W (Wt[m][h][k']=w[h][k'][m]).
__global__ __launch_bounds__(256) void k_pre(const float* __restrict__ wr,
                                             const float* __restrict__ wi,
                                             float* __restrict__ T2,
                                             float* __restrict__ Wtr,
                                             float* __restrict__ Wti) {
    const int t = threadIdx.x;
    if (blockIdx.x < 256) {
        int idx = blockIdx.x * 256 + t;     // 0 .. 65535
        int s = idx >> 4, k = idx & 15;
        int r = (k * s) & (SS - 1);         // exact angle reduction
        float th = (float)r * (6.28318530717958647692f / (float)SS);
        float sn, cn;
        sincosf(th, &sn, &cn);
        T2[s * 32 + 2 * k]     = cn;
        T2[s * 32 + 2 * k + 1] = sn;
    } else {
        __shared__ float lds[4096 + 256];
        int bid = blockIdx.x - 256;         // 0..511
        int h = bid & 255, y = bid >> 8;
        const float* src = (y == 0 ? wr : wi) + (size_t)h * 4096;
        float* dst = (y == 0 ? Wtr : Wti);
#pragma unroll
        for (int j = 0; j < 16; j++) {
            int i = j * 256 + t;
            lds[i + (i >> 4)] = src[i];
        }
        __syncthreads();
#pragma unroll
        for (int m = 0; m < 16; m++) {
            int i = t * 16 + m;
            dst[(size_t)m * (HH * HH) + (size_t)h * HH + t] = lds[i + (i >> 4)];
        }
    }
}

// Branchless exact-GELU via A&S 7.1.26 erf (|err| ~ 1.5e-7).
__device__ __forceinline__ float fast_gelu(float y) {
    float x  = fabsf(y) * 0.70710678118654752f;
    float t  = __builtin_amdgcn_rcpf(fmaf(0.3275911f, x, 1.0f));
    float e  = __expf(-x * x);
    float p  = fmaf(fmaf(fmaf(fmaf(1.061405429f, t, -1.453152027f), t,
                   1.421413741f), t, -0.284496736f), t, 0.254829592f) * t;
    float erfabs = fmaf(-p, e, 1.0f);
    return fmaf(0.5f * fabsf(y), erfabs, 0.5f * y);
}

// Stage 1: pruned DFT, half-fold (rows s and s+4096), twiddles in LDS.
// Wave w owns k in {4w..4w+3}; lane l owns h-quad [4l, 4l+4) (float4 loads).
// X_re[k] = sum_{s<4096} cos(2pi k s/S)*(even k ? u : d), u=x_s+x_{s+4096},
// d=x_s-x_{s+4096}; X_im analogous with sin.  The block's 64-row twiddle
// strip (8 KB) is staged to LDS once; inner-loop twiddle reads are
// uniform-address ds_read_b128 (broadcast, conflict-free, no VMEM).
__global__ __launch_bounds__(256) void k_dft(const float* __restrict__ x,
                                             const float* __restrict__ T2,
                                             float* __restrict__ Xp) {
    const int c = blockIdx.x, b = blockIdx.y, t = threadIdx.x;
    const int w = t >> 6, l = t & 63;
    const int s0 = c * DL;

    __shared__ float tw_s[DL * 32];              // 8 KB
    {
        const float4* src = (const float4*)(T2 + (size_t)s0 * 32);
        float4* dst = (float4*)tw_s;
        dst[t * 2]     = src[t * 2];             // 2048 floats, coalesced
        dst[t * 2 + 1] = src[t * 2 + 1];
    }
    __syncthreads();

    const float* x0 = x + (size_t)b * SS * HH + (size_t)s0 * HH + 4 * l;
    const float* x1 = x0 + (size_t)(SS / 2) * HH;

    float cs[4][4], sn[4][4];
#pragma unroll
    for (int k = 0; k < 4; k++)
#pragma unroll
        for (int q = 0; q < 4; q++) { cs[k][q] = 0.f; sn[k][q] = 0.f; }

#pragma unroll 4
    for (int i = 0; i < DL; i++) {
        float4 xa = *(const float4*)(x0 + (size_t)i * HH);
        float4 xb = *(const float4*)(x1 + (size_t)i * HH);
        float u[4] = { xa.x + xb.x, xa.y + xb.y, xa.z + xb.z, xa.w + xb.w };
        float d[4] = { xa.x - xb.x, xa.y - xb.y, xa.z - xb.z, xa.w - xb.w };
        const float* tw8 = tw_s + i * 32 + w * 8;
        float4 t0 = *(const float4*)(tw8);       // cos/sin for k=4w, 4w+1
        float4 t1 = *(const float4*)(tw8 + 4);   // cos/sin for k=4w+2, 4w+3
#pragma unroll
        for (int q = 0; q < 4; q++) {
            cs[0][q] = fmaf(t0.x, u[q], cs[0][q]);   // k=4w   even -> u
            sn[0][q] = fmaf(t0.y, u[q], sn[0][q]);
            cs[1][q] = fmaf(t0.z, d[q], cs[1][q]);   // k=4w+1 odd  -> d
            sn[1][q] = fmaf(t0.w, d[q], sn[1][q]);
            cs[2][q] = fmaf(t1.x, u[q], cs[2][q]);   // k=4w+2 even -> u
            sn[2][q] = fmaf(t1.y, u[q], sn[2][q]);
            cs[3][q] = fmaf(t1.z, d[q], cs[3][q]);   // k=4w+3 odd  -> d
            sn[3][q] = fmaf(t1.w, d[q], sn[3][q]);
        }
    }

    size_t base = ((size_t)(b * DNC + c) * MM) * (2 * HH) + 4 * l;
#pragma unroll
    for (int kk = 0; kk < 4; kk++) {
        int k = 4 * w + kk;
        *(float4*)(Xp + base + (size_t)k * (2 * HH)) =
            make_float4(cs[kk][0], cs[kk][1], cs[kk][2], cs[kk][3]);
        *(float4*)(Xp + base + (size_t)k * (2 * HH) + HH) =
            make_float4(sn[kk][0], sn[kk][1], sn[kk][2], sn[kk][3]);
    }
}

// Stage 2 (fused reduce+mix, h-split by 2): block (m, b, q) handles h-half
// [q*128, q*128+128).  Phase A: sum Xp over 64 partials (two p-halves across
// thread groups, LDS-combined).  Phase B: partial O[k'] over this h-half:
// X = cs - i*sn;  O[k'] = sum_h X[h]*(wr+i*wi)[h,k',m];
// ABp[q] = scale*Re(O), ABp[q]+HH = -scale*Im(O); k_synth sums the 2 halves.
__global__ __launch_bounds__(256) void k_mix(const float* __restrict__ Xp,
                                             const float* __restrict__ Wtr,
                                             const float* __restrict__ Wti,
                                             float* __restrict__ ABp) {
    const int m = blockIdx.x, b = blockIdx.y, q = blockIdx.z, t = threadIdx.x;
    const int h0 = q * 128;
    __shared__ float tmp[2][2][128];
    __shared__ float xr_s[128], xs_s[128];

    {   // phase A: hh = t&127, p-half = t>>7 (32 p's each)
        int hh = t & 127, ph = t >> 7;
        float s0 = 0.f, s1 = 0.f;
        size_t base = (((size_t)b * DNC + ph * 32) * MM + m) * (2 * HH) + h0 + hh;
        const size_t ps = (size_t)MM * 2 * HH;
#pragma unroll 4
        for (int p = 0; p < 32; p++) {
            s0 += Xp[base + (size_t)p * ps];
            s1 += Xp[base + (size_t)p * ps + HH];
        }
        tmp[ph][0][hh] = s0;
        tmp[ph][1][hh] = s1;
        __syncthreads();
        if (t < 128) {
            xr_s[t] = tmp[0][0][t] + tmp[1][0][t];
            xs_s[t] = tmp[0][1][t] + tmp[1][1][t];
        }
        __syncthreads();
    }

    // phase B: t = k', loop over this h-half
    const float* wr_m = Wtr + (size_t)m * (HH * HH) + (size_t)h0 * HH;
    const float* wi_m = Wti + (size_t)m * (HH * HH) + (size_t)h0 * HH;
    float re = 0.f, im = 0.f;
#pragma unroll 8
    for (int hh = 0; hh < 128; hh++) {
        float a  = wr_m[(size_t)hh * HH + t];   // lane-contiguous, 1KB/wave
        float bw = wi_m[(size_t)hh * HH + t];
        float xr = xr_s[hh];                    // LDS broadcast
        float xs = xs_s[hh];
        re = fmaf(xr, a, re);  re = fmaf(xs, bw, re);
        im = fmaf(xr, bw, im); im = fmaf(-xs, a, im);
    }
    float scale = (m == 0 ? 1.f : 2.f) / (float)SS;
    size_t o = (size_t)q * QOFF + (((size_t)b * MM + m) * 2) * HH + t;
    ABp[o]      = scale * re;
    ABp[o + HH] = -scale * im;
}

// Stage 3: folded synthesis + GELU.  4 outputs per table row:
// y[v]=Pp+Qp, y[4096-v]=Pm-Qm, y[4096+v]=Pm+Qm, y[8192-v]=Pp-Qp
__global__ __launch_bounds__(256) void k_synth(const float* __restrict__ ABp,
                                               const float* __restrict__ T2,
                                               float* __restrict__ out) {
    const int c = blockIdx.x, b = blockIdx.y, h = threadIdx.x;
    float a[MM], bc[MM];
#pragma unroll
    for (int k = 0; k < MM; k++) {
        size_t o = (((size_t)b * MM + k) * 2) * HH + h;
        a[k]  = ABp[o]      + ABp[o + QOFF];
        bc[k] = ABp[o + HH] + ABp[o + HH + QOFF];
    }
    const int nv = (c == SNC - 1) ? 1 : SCH;
    const int v0 = c * SCH;
    float* ob = out + (size_t)b * SS * HH + h;

#pragma unroll 2
    for (int i = 0; i < nv; i++) {
        int v = v0 + i;
        const float4* tw4 = (const float4*)(T2 + (size_t)v * 32);
        float Pe = 0.f, Po = 0.f, Qe = 0.f, Qo = 0.f;
#pragma unroll
        for (int j = 0; j < 8; j++) {
            float4 t = tw4[j];
            Pe = fmaf(a[2 * j],      t.x, Pe);
            Qe = fmaf(bc[2 * j],     t.y, Qe);
            Po = fmaf(a[2 * j + 1],  t.z, Po);
            Qo = fmaf(bc[2 * j + 1], t.w, Qo);
        }
        float Pp = Pe + Po, Pm = Pe - Po, Qp = Qe + Qo, Qm = Qe - Qo;
        ob[(size_t)v * HH]                        = fast_gelu(Pp + Qp);
        ob[(size_t)(SS / 2 - v) * HH]             = fast_gelu(Pm - Qm);
        ob[(size_t)(SS / 2 + v) * HH]             = fast_gelu(Pm + Qm);
        ob[(size_t)((SS - v) & (SS - 1)) * HH]    = fast_gelu(Pp - Qp);
    }
}

extern "C" void kernel_launch(void* const* d_in, const int* in_sizes, int n_in,
                              void* d_out, int out_size, void* d_ws, size_t ws_size,
                              hipStream_t stream) {
    const float* x   = (const float*)d_in[0];
    const float* w_r = (const float*)d_in[1];
    const float* w_i = (const float*)d_in[2];
    float* out = (float*)d_out;
    float* ws  = (float*)d_ws;

    float* T2  = ws;                              // 131072 floats
    float* ABp = ws + 131072;                     // 262144 floats
    float* Xp  = out;                             // 8.39M floats scratch
    float* Wtr = out + (size_t)16 * 1024 * 1024;  // 1M floats scratch
    float* Wti = out + (size_t)17 * 1024 * 1024;  // 1M floats scratch

    hipLaunchKernelGGL(k_pre,   dim3(768), dim3(256), 0, stream, w_r, w_i, T2, Wtr, Wti);
    hipLaunchKernelGGL(k_dft,   dim3(DNC, BB), dim3(256), 0, stream, x, T2, Xp);
    hipLaunchKernelGGL(k_mix,   dim3(MM, BB, 2), dim3(256), 0, stream, Xp, Wtr, Wti, ABp);
    hipLaunchKernelGGL(k_synth, dim3(SNC, BB), dim3(256), 0, stream, ABp, T2, out);
}